// Round 3
// baseline (1224.663 us; speedup 1.0000x reference)
//
#include <hip/hip_runtime.h>

// PerturbationModel: scores = counts @ log_mix^T (+ log comm bias), LSE over K=20, grand sum.
// G=3 S=10 N=5000 K=20 O=1000. counts 600 MB fp32 -> memory-bound, HBM floor ~95 us.
//
// R1: __launch_bounds__(512,4) spilled acc -> 1049 us. R2: (512,2) -> ~320 us (bench 885
// incl ~565 us harness restore overhead; kernel hidden below fill dispatches in top-5).
// R3: k-split layout (acc 80->40 VGPR) + cur/nxt double-buffered chunk prefetch +
// cross-granule prefetch under the reduction epilogue. Target: latency-bound -> BW-bound.

#define EPSF 1e-6f
constexpr int Gc = 3, Sc = 10, Nc = 5000, Kc = 20, Oc = 1000;
constexpr int ROWS_PER_G = Sc * Nc;                 // 50000
constexpr int GRAN_ROWS  = 4;                       // rows per wave-granule (shared by both k-halves)
constexpr int GRANS_PER_G = ROWS_PER_G / GRAN_ROWS; // 12500 (exact; granule never straddles s)
constexpr int KH = Kc / 2;                          // 10 k per half
constexpr int LM_ELEMS = Kc * Oc;                   // 20000
constexpr int LM_ALLOC = LM_ELEMS + 32;             // guard pad for tail-lane b128 reads

// 32-lane-group sum via DPP (VALU pipe only). Result valid in lanes 31 and 63.
__device__ __forceinline__ float red32(float v) {
  v += __int_as_float(__builtin_amdgcn_update_dpp(0, __float_as_int(v), 0x111, 0xF, 0xF, true)); // row_shr:1
  v += __int_as_float(__builtin_amdgcn_update_dpp(0, __float_as_int(v), 0x112, 0xF, 0xF, true)); // row_shr:2
  v += __int_as_float(__builtin_amdgcn_update_dpp(0, __float_as_int(v), 0x114, 0xF, 0xF, true)); // row_shr:4
  v += __int_as_float(__builtin_amdgcn_update_dpp(0, __float_as_int(v), 0x118, 0xF, 0xF, true)); // row_shr:8
  v += __int_as_float(__builtin_amdgcn_update_dpp(0, __float_as_int(v), 0x142, 0xF, 0xF, true)); // row_bcast:15
  return v;
}

__global__ __launch_bounds__(512, 2) void perturb_kernel(
    const float* __restrict__ counts, const float* __restrict__ otu,
    const float* __restrict__ comm,   const float* __restrict__ cw,
    const float* __restrict__ cc,     const float* __restrict__ gamma_p,
    float* __restrict__ out) {
  // LDS: 80128 + 800 = 80928 B -> 2 blocks/CU (161856 <= 163840)
  __shared__ float s_lm[LM_ALLOC];     // [k][o] log(mix+eps) for this block's g
  __shared__ float s_bias[Sc * Kc];    // [s][k] log(comm+eps) for this g

  const int tid  = threadIdx.x;
  const int bid  = blockIdx.x;
  const int g    = bid % Gc;
  const int bg   = bid / Gc;
  const int blocksg = (gridDim.x + (Gc - 1) - g) / Gc;

  const float cwg = cw[g];
  const float gam = gamma_p[0];

  // ---- stage log_mix + bias into LDS ----
  for (int idx = tid; idx < LM_ALLOC; idx += blockDim.x) {
    float v = 0.f;
    if (idx < LM_ELEMS) {
      int o = idx % Oc;
      float mix = otu[idx] * (1.f - cwg) + cwg * cc[g * Oc + o];
      v = __logf(mix + EPSF);
    }
    s_lm[idx] = v;
  }
  for (int idx = tid; idx < Sc * Kc; idx += blockDim.x) {
    int s = idx / Kc, k = idx - s * Kc;
    s_bias[idx] = __logf(comm[(k * Gc + g) * Sc + s] + EPSF);
  }
  __syncthreads();

  const int wave = tid >> 6;
  const int lane = tid & 63;
  const int kh   = lane >> 5;          // k-half: 0 -> k in [0,10), 1 -> [10,20)
  const int k0   = kh * KH;
  const int osub = lane & 31;          // o-column group within 128-o chunk
  const int ocol = osub << 2;

  const int waveg  = bg * 8 + wave;
  const int nwaveg = blocksg * 8;

  float lsum = 0.f;                    // valid in lane 31

  int gr = waveg;
  float4 cur0, cur1, cur2, cur3;
  const float* gbase = counts + (size_t)g * ROWS_PER_G * Oc;

  if (gr < GRANS_PER_G) {              // prime: chunk 0 of first granule
    const float* base = gbase + (size_t)gr * GRAN_ROWS * Oc + ocol;
    cur0 = *(const float4*)(base + 0 * Oc);
    cur1 = *(const float4*)(base + 1 * Oc);
    cur2 = *(const float4*)(base + 2 * Oc);
    cur3 = *(const float4*)(base + 3 * Oc);
  }

  for (; gr < GRANS_PER_G; gr += nwaveg) {
    const int row0 = gr * GRAN_ROWS;
    const float* base = gbase + (size_t)row0 * Oc + ocol;

    float acc[GRAN_ROWS][KH];
#pragma unroll
    for (int r = 0; r < GRAN_ROWS; ++r)
#pragma unroll
      for (int k = 0; k < KH; ++k) acc[r][k] = 0.f;

#pragma unroll
    for (int j = 0; j < 7; ++j) {
      // prefetch chunk j+1 (j==6 prefetches the predicated tail)
      float4 n0 = {0,0,0,0}, n1 = {0,0,0,0}, n2 = {0,0,0,0}, n3 = {0,0,0,0};
      if (j < 6 || osub < 26) {
        const float* nb = base + (j + 1) * 128;
        n0 = *(const float4*)(nb + 0 * Oc);
        n1 = *(const float4*)(nb + 1 * Oc);
        n2 = *(const float4*)(nb + 2 * Oc);
        n3 = *(const float4*)(nb + 3 * Oc);
      }
      const int ob = j * 128 + ocol;
#pragma unroll
      for (int k = 0; k < KH; ++k) {
        float4 L = *(const float4*)&s_lm[(k0 + k) * Oc + ob];
        acc[0][k] += cur0.x * L.x + cur0.y * L.y + cur0.z * L.z + cur0.w * L.w;
        acc[1][k] += cur1.x * L.x + cur1.y * L.y + cur1.z * L.z + cur1.w * L.w;
        acc[2][k] += cur2.x * L.x + cur2.y * L.y + cur2.z * L.z + cur2.w * L.w;
        acc[3][k] += cur3.x * L.x + cur3.y * L.y + cur3.z * L.z + cur3.w * L.w;
      }
      cur0 = n0; cur1 = n1; cur2 = n2; cur3 = n3;
    }
    // tail chunk compute (o in [896,1000); guard pad covers lm reads past 1000)
    {
      const int ob = 896 + ocol;
#pragma unroll
      for (int k = 0; k < KH; ++k) {
        float4 L = *(const float4*)&s_lm[(k0 + k) * Oc + ob];
        acc[0][k] += cur0.x * L.x + cur0.y * L.y + cur0.z * L.z + cur0.w * L.w;
        acc[1][k] += cur1.x * L.x + cur1.y * L.y + cur1.z * L.z + cur1.w * L.w;
        acc[2][k] += cur2.x * L.x + cur2.y * L.y + cur2.z * L.z + cur2.w * L.w;
        acc[3][k] += cur3.x * L.x + cur3.y * L.y + cur3.z * L.z + cur3.w * L.w;
      }
    }

    // cross-granule prefetch: next granule's chunk 0, hidden under the epilogue
    const int grn = gr + nwaveg;
    if (grn < GRANS_PER_G) {
      const float* nb = gbase + (size_t)grn * GRAN_ROWS * Oc + ocol;
      cur0 = *(const float4*)(nb + 0 * Oc);
      cur1 = *(const float4*)(nb + 1 * Oc);
      cur2 = *(const float4*)(nb + 2 * Oc);
      cur3 = *(const float4*)(nb + 3 * Oc);
    }

    // reduce over the 32 o-lanes (DPP, VALU pipe). lanes 31/63 hold per-half sums.
#pragma unroll
    for (int r = 0; r < GRAN_ROWS; ++r)
#pragma unroll
      for (int k = 0; k < KH; ++k) acc[r][k] = red32(acc[r][k]);

    if ((lane & 31) == 31) {
      const int s = row0 / Nc;                    // granule never straddles an s boundary
      const float* bp = &s_bias[s * Kc + k0];
#pragma unroll
      for (int r = 0; r < GRAN_ROWS; ++r) {
        float m_h = -3.4e38f;
#pragma unroll
        for (int k = 0; k < KH; ++k) {
          float x = acc[r][k] + bp[k];
          acc[r][k] = x;
          m_h = fmaxf(m_h, x);
        }
        float s_h = 0.f;
#pragma unroll
        for (int k = 0; k < KH; ++k) s_h += __expf(gam * (acc[r][k] - m_h));
        // combine halves: lanes 31 <-> 63
        float m_o = __shfl_xor(m_h, 32);
        float s_o = __shfl_xor(s_h, 32);
        float m = fmaxf(m_h, m_o);
        float ss = s_h * __expf(gam * (m_h - m)) + s_o * __expf(gam * (m_o - m));
        if (lane == 31) lsum += m + __logf(ss);
      }
    }
  }

  if (lane == 31) atomicAdd(out, lsum);
}

extern "C" void kernel_launch(void* const* d_in, const int* in_sizes, int n_in,
                              void* d_out, int out_size, void* d_ws, size_t ws_size,
                              hipStream_t stream) {
  const float* counts = (const float*)d_in[0];
  const float* otu    = (const float*)d_in[1];
  const float* comm   = (const float*)d_in[2];
  const float* cw     = (const float*)d_in[3];
  const float* cc     = (const float*)d_in[4];
  const float* gam    = (const float*)d_in[5];
  float* out = (float*)d_out;

  hipMemsetAsync(out, 0, sizeof(float), stream);
  hipLaunchKernelGGL(perturb_kernel, dim3(512), dim3(512), 0, stream,
                     counts, otu, comm, cw, cc, gam, out);
}